// Round 8
// baseline (99.351 us; speedup 1.0000x reference)
//
#include <hip/hip_runtime.h>
#include <stdint.h>

#define KCODES  1024
#define CDIM    64
#define SPATIAL 32768
#define NPOS    65536
#define NEL     4194304

// d_out layout (floats), outputs concatenated in reference return order
#define OUT_Q    0
#define OUT_LOSS 4194304
#define OUT_IDX  4194305
#define OUT_SUM  4259841
#define OUT_EMB  4260097

// ws: 32 sets x 8KB {Ah0,Al0,Ah1,Al1,Ah2,Al2,Ah3,Al3} (1KB chunks, lane-linear),
// then eiExp[32][2][16] f32 at EIEXP: per-lane C-init vectors (-0.5*||e||^2)
#define NSET  32
#define SETB  8192
#define EIEXP 262144
#define BPOS  128
#define NPASS 4

typedef _Float16 half8  __attribute__((ext_vector_type(8)));
typedef float    f32x4  __attribute__((ext_vector_type(4)));
typedef float    f32x16 __attribute__((ext_vector_type(16)));

// ---- prep: fragment-swizzle codebook (32x32x16 A-frags), eiExp, zero, passthrough ----
__global__ void prep_emb(const float* __restrict__ emb, char* __restrict__ ws,
                         float* __restrict__ out) {
    int gt = blockIdx.x * 256 + threadIdx.x;        // 64 blocks -> 0..16383
    if (gt == 0) out[OUT_LOSS] = 0.f;
    if (gt < 256) out[OUT_SUM + gt] = 0.f;
    {   // embedding passthrough (OUT_EMB odd offset -> scalar stores)
        float4 v = *(const float4*)(emb + (size_t)gt * 4);
        float* o = out + OUT_EMB + (size_t)gt * 4;
        o[0] = v.x; o[1] = v.y; o[2] = v.z; o[3] = v.w;
    }
    if (gt < 8192) {                                 // one (code, 8-ch octet) each
        int k = gt >> 3, oct = gt & 7;
        int set = k >> 5, row = k & 31;
        int ks = oct >> 1, hc = oct & 1;             // c = ks*16 + hc*8 + i
        const float* e = emb + (size_t)k * CDIM + oct * 8;
        char* rec = ws + (size_t)set * SETB;
        // A-frag: lane l = hc*32+row holds 8 fp16 at chunk(ks,hi/lo) + l*16
        _Float16* hi = (_Float16*)(rec + (ks * 2 + 0) * 1024 + (hc * 32 + row) * 16);
        _Float16* lo = (_Float16*)(rec + (ks * 2 + 1) * 1024 + (hc * 32 + row) * 16);
        float s2 = 0.f;
        half8 hv, lv;
#pragma unroll
        for (int i = 0; i < 8; ++i) {
            float v = e[i];
            s2 = fmaf(v, v, s2);
            _Float16 h = (_Float16)v;
            hv[i] = h;
            lv[i] = (_Float16)(v - (float)h);
        }
        *(half8*)hi = hv;
        *(half8*)lo = lv;
        s2 += __shfl_xor(s2, 1);                     // reduce over the octet group
        s2 += __shfl_xor(s2, 2);
        s2 += __shfl_xor(s2, 4);
        if (oct == 0) {
            // C/D row = (q&3) + 8*(q>>2) + 4h  ->  h = bit2(row), q = (row&3)|((row>>3)<<2)
            int hh = (row >> 2) & 1;
            int q  = (row & 3) | ((row >> 3) << 2);
            ((float*)(ws + EIEXP))[(set * 2 + hh) * 16 + q] = -0.5f * s2;
        }
    }
}

// ---- main VQ kernel ----
// Grid 512 x 512 thr (8 waves), 2 blocks/CU, 4 waves/SIMD. Block owns 128 pos.
// CODES-RESIDENT: per pass, wave wv holds A-frags of codes [set*32, set*32+32)
// in 32 VGPRs (set = pass*8+wv); positions stream as B-frags from LDS (built
// once in prologue, read-only). Main loop: ZERO global loads, ZERO barriers.
// ei folded via MFMA C-operand (eiExp). Score = x.e - 0.5||e||^2, argmax==argmin.
__global__ __launch_bounds__(512, 4) void vq_kernel(
        const float* __restrict__ in, const float* __restrict__ emb,
        const char* __restrict__ wsA, float* __restrict__ out) {
    __shared__ float xl[CDIM * 129];                 // 33 KB x transpose tile
    __shared__ __align__(16) char bfr[4 * 4 * 2 * 1024];  // 32 KB B-frags [t][ks][hl][lane*16]
    __shared__ float candS[8][BPOS];                 // per-wave per-pos best score
    __shared__ int   candK[8][BPOS];
    __shared__ int   kwin[BPOS];
    __shared__ float lred[8];

    const int tid  = threadIdx.x;
    const int lane = tid & 63, wv = tid >> 6;        // 8 waves
    const int col  = lane & 31, h = lane >> 5;
    const int p0   = blockIdx.x * BPOS;
    const int b    = p0 >> 15;                       // 128-tile never straddles batch
    const int s0   = p0 & 32767;
    const float* xin = in + (size_t)b * (CDIM * SPATIAL) + s0;

    // ---- prologue: x -> xl, init cand ----
    {
        int p = tid & 127, cq = tid >> 7;            // 4 ch-groups of 16
#pragma unroll
        for (int j = 0; j < 16; ++j) {
            int c = cq * 16 + j;
            xl[c * 129 + p] = xin[(size_t)c * SPATIAL + p];
        }
    }
#pragma unroll
    for (int i = tid; i < 8 * BPOS; i += 512) {
        candS[i >> 7][i & 127] = -3.402823466e38f;
        candK[i >> 7][i & 127] = 0;
    }
    __syncthreads();

    // ---- build B-frags (hi/lo fp16) from xl; layout matches MFMA B operand:
    // lane l: col = l&31 (position), k-local = (l>>5)*8 + i ----
#pragma unroll
    for (int s = tid; s < 1024; s += 512) {
        int t = s >> 8, ks = (s >> 6) & 3, l = s & 63;
        int pos = t * 32 + (l & 31);
        int c0  = ks * 16 + (l >> 5) * 8;
        half8 hv, lv;
#pragma unroll
        for (int i = 0; i < 8; ++i) {
            float v = xl[(c0 + i) * 129 + pos];
            _Float16 hh = (_Float16)v;
            hv[i] = hh;
            lv[i] = (_Float16)(v - (float)hh);
        }
        *(half8*)(bfr + (size_t)((t * 4 + ks) * 2 + 0) * 1024 + l * 16) = hv;
        *(half8*)(bfr + (size_t)((t * 4 + ks) * 2 + 1) * 1024 + l * 16) = lv;
    }
    __syncthreads();

    // ---- main: 4 passes x 4 tiles; A resident in regs, B from LDS, no barriers ----
#pragma unroll 1
    for (int pass = 0; pass < NPASS; ++pass) {
        const int set = pass * 8 + wv;
        const char* rec = wsA + (size_t)set * SETB;
        const char* ap  = rec + (size_t)lane * 16;
        half8 ah0 = *(const half8*)(ap);             // A-frags: 32 codes, once per pass
        half8 al0 = *(const half8*)(ap + 1024);
        half8 ah1 = *(const half8*)(ap + 2048);
        half8 al1 = *(const half8*)(ap + 3072);
        half8 ah2 = *(const half8*)(ap + 4096);
        half8 al2 = *(const half8*)(ap + 5120);
        half8 ah3 = *(const half8*)(ap + 6144);
        half8 al3 = *(const half8*)(ap + 7168);
        f32x16 eiv = *(const f32x16*)((const float*)(wsA + EIEXP) + (set * 2 + h) * 16);
        const int kbase = set * 32 + 4 * h;

#pragma unroll
        for (int t = 0; t < 4; ++t) {
            const char* bp = bfr + (size_t)t * 8192 + (size_t)lane * 16;
            half8 bh0 = *(const half8*)(bp);
            half8 bl0 = *(const half8*)(bp + 1024);
            half8 bh1 = *(const half8*)(bp + 2048);
            half8 bl1 = *(const half8*)(bp + 3072);
            half8 bh2 = *(const half8*)(bp + 4096);
            half8 bl2 = *(const half8*)(bp + 5120);
            half8 bh3 = *(const half8*)(bp + 6144);
            half8 bl3 = *(const half8*)(bp + 7168);
            f32x16 a;
            a = __builtin_amdgcn_mfma_f32_32x32x16_f16(ah0, bh0, eiv, 0, 0, 0);
            a = __builtin_amdgcn_mfma_f32_32x32x16_f16(ah0, bl0, a, 0, 0, 0);
            a = __builtin_amdgcn_mfma_f32_32x32x16_f16(al0, bh0, a, 0, 0, 0);
            a = __builtin_amdgcn_mfma_f32_32x32x16_f16(ah1, bh1, a, 0, 0, 0);
            a = __builtin_amdgcn_mfma_f32_32x32x16_f16(ah1, bl1, a, 0, 0, 0);
            a = __builtin_amdgcn_mfma_f32_32x32x16_f16(al1, bh1, a, 0, 0, 0);
            a = __builtin_amdgcn_mfma_f32_32x32x16_f16(ah2, bh2, a, 0, 0, 0);
            a = __builtin_amdgcn_mfma_f32_32x32x16_f16(ah2, bl2, a, 0, 0, 0);
            a = __builtin_amdgcn_mfma_f32_32x32x16_f16(al2, bh2, a, 0, 0, 0);
            a = __builtin_amdgcn_mfma_f32_32x32x16_f16(ah3, bh3, a, 0, 0, 0);
            a = __builtin_amdgcn_mfma_f32_32x32x16_f16(ah3, bl3, a, 0, 0, 0);
            a = __builtin_amdgcn_mfma_f32_32x32x16_f16(al3, bh3, a, 0, 0, 0);

            // fold: k(q) = kbase + (q&3) + 8*(q>>2), strictly ascending in q
            // -> linear strict-> scan keeps smallest k on ties
            float bs = a[0];
            int   bk = kbase;
#pragma unroll
            for (int q = 1; q < 16; ++q) {
                float sc = a[q];
                int   kk = kbase + (q & 3) + 8 * (q >> 2);
                if (sc > bs) { bs = sc; bk = kk; }
            }
            // h-combine (k interleaves across h -> lex)
            {
                float os = __shfl_xor(bs, 32);
                int   ok = __shfl_xor(bk, 32);
                if (os > bs || (os == bs && ok < bk)) { bs = os; bk = ok; }
            }
            // per-wave running best in LDS (owner-wave RMW, no race);
            // passes ascend in k -> strict > keeps smaller k on ties
            if (h == 0) {
                int pc = t * 32 + col;
                float cs = candS[wv][pc];
                if (bs > cs) { candS[wv][pc] = bs; candK[wv][pc] = bk; }
            }
        }
    }
    __syncthreads();

    // ---- final 8-way lex combine, write indices ----
    if (tid < BPOS) {
        int p = tid;
        float bs = candS[0][p];
        int   bk = candK[0][p];
#pragma unroll
        for (int w = 1; w < 8; ++w) {
            float sc = candS[w][p];
            int   kk = candK[w][p];
            if (sc > bs || (sc == bs && kk < bk)) { bs = sc; bk = kk; }
        }
        kwin[p] = bk;
        out[OUT_IDX + p0 + p] = (float)bk;
    }
    __syncthreads();

    // ---- epilogue: coalesced q stores, exact f32 x re-read (L3-hot), loss ----
    float lsum = 0.f;
    {
        int p = tid & 127, cq = tid >> 7;
        int kk = kwin[p];
        const float* eb = emb + (size_t)kk * CDIM;
        float* q = out + OUT_Q + (size_t)b * (CDIM * SPATIAL) + s0;
#pragma unroll
        for (int j = 0; j < 16; ++j) {
            int c = cq * 16 + j;
            float x = xin[(size_t)c * SPATIAL + p];
            float e = eb[c];
            float d = e - x;                         // stop_grad(q - x)
            lsum = fmaf(d, d, lsum);
            q[(size_t)c * SPATIAL + p] = x + d;      // straight-through
        }
    }
#pragma unroll
    for (int off = 32; off > 0; off >>= 1) lsum += __shfl_down(lsum, off);
    if (lane == 0) lred[wv] = lsum;
    __syncthreads();
    if (tid == 0) {
        float t = 0.f;
#pragma unroll
        for (int w = 0; w < 8; ++w) t += lred[w];
        atomicAdd(out + OUT_LOSS, t * (0.25f / (float)NEL));
    }
}

extern "C" void kernel_launch(void* const* d_in, const int* in_sizes, int n_in,
                              void* d_out, int out_size, void* d_ws, size_t ws_size,
                              hipStream_t stream) {
    const float* in  = (const float*)d_in[0];   // [2,64,32,32,32] f32
    const float* emb = (const float*)d_in[1];   // [1024,64] f32
    float* out = (float*)d_out;
    char*  ws  = (char*)d_ws;                   // 266,240 B used

    prep_emb<<<64, 256, 0, stream>>>(emb, ws, out);
    vq_kernel<<<NPOS / BPOS, 512, 0, stream>>>(in, emb, ws, out);
}

// Round 9
// 49.037 us; speedup vs baseline: 2.0260x; 2.0260x over previous
//
#include <hip/hip_runtime.h>
#include <stdint.h>

#define KCODES  1024
#define CDIM    64
#define SPATIAL 32768
#define NPOS    65536
#define NEL     4194304

// d_out layout (floats), outputs concatenated in reference return order
#define OUT_Q    0
#define OUT_LOSS 4194304
#define OUT_IDX  4194305
#define OUT_SUM  4259841
#define OUT_EMB  4260097

// ws: 32 sets x 8KB {Ah0,Al0,Ah1,Al1,Ah2,Al2,Ah3,Al3} (1KB chunks, lane-linear),
// then eiExp[32][2][16] f32 at EIEXP: per-lane C-init vectors (-0.5*||e||^2)
#define NSET  32
#define SETB  8192
#define EIEXP 262144
#define BPOS  256

typedef _Float16 half8  __attribute__((ext_vector_type(8)));
typedef float    f32x4  __attribute__((ext_vector_type(4)));
typedef float    f32x16 __attribute__((ext_vector_type(16)));

// ---- prep: fragment-swizzle codebook (32x32x16 A-frags), eiExp, zero, passthrough ----
__global__ void prep_emb(const float* __restrict__ emb, char* __restrict__ ws,
                         float* __restrict__ out) {
    int gt = blockIdx.x * 256 + threadIdx.x;        // 64 blocks -> 0..16383
    if (gt == 0) out[OUT_LOSS] = 0.f;
    if (gt < 256) out[OUT_SUM + gt] = 0.f;
    {   // embedding passthrough (OUT_EMB odd offset -> scalar stores)
        float4 v = *(const float4*)(emb + (size_t)gt * 4);
        float* o = out + OUT_EMB + (size_t)gt * 4;
        o[0] = v.x; o[1] = v.y; o[2] = v.z; o[3] = v.w;
    }
    if (gt < 8192) {                                 // one (code, 8-ch octet) each
        int k = gt >> 3, oct = gt & 7;
        int set = k >> 5, row = k & 31;
        int ks = oct >> 1, hc = oct & 1;             // c = ks*16 + hc*8 + i
        const float* e = emb + (size_t)k * CDIM + oct * 8;
        char* rec = ws + (size_t)set * SETB;
        // A-frag: lane l = hc*32+row holds 8 fp16 at chunk(ks,hi/lo) + l*16
        _Float16* hi = (_Float16*)(rec + (ks * 2 + 0) * 1024 + (hc * 32 + row) * 16);
        _Float16* lo = (_Float16*)(rec + (ks * 2 + 1) * 1024 + (hc * 32 + row) * 16);
        float s2 = 0.f;
        half8 hv, lv;
#pragma unroll
        for (int i = 0; i < 8; ++i) {
            float v = e[i];
            s2 = fmaf(v, v, s2);
            _Float16 h = (_Float16)v;
            hv[i] = h;
            lv[i] = (_Float16)(v - (float)h);
        }
        *(half8*)hi = hv;
        *(half8*)lo = lv;
        s2 += __shfl_xor(s2, 1);                     // reduce over the octet group
        s2 += __shfl_xor(s2, 2);
        s2 += __shfl_xor(s2, 4);
        if (oct == 0) {
            // C/D row = (q&3) + 8*(q>>2) + 4h  ->  h = bit2(row), q = (row&3)|((row>>3)<<2)
            int hh = (row >> 2) & 1;
            int q  = (row & 3) | ((row >> 3) << 2);
            ((float*)(ws + EIEXP))[(set * 2 + hh) * 16 + q] = -0.5f * s2;
        }
    }
}

// async global->LDS, 16B per lane
#define GLDS16(GSRC, LDST)                                                     \
    __builtin_amdgcn_global_load_lds(                                          \
        (const __attribute__((address_space(1))) void*)(GSRC),                 \
        (__attribute__((address_space(3))) void*)(LDST), 16, 0, 0)

// ---- main VQ kernel ----
// Grid 256 x 512 thr (8 waves). Block owns 256 positions; wave owns 32 (one
// 32-col B tile held in 32 VGPRs). All waves scan all 1024 codes as 32 sets
// of 32 via mfma_f32_32x32x16_f16, fp16 2-way split (3 terms). Codebook sets
// in a 3-slot LDS ring staged 2 ahead (counted vmcnt(1), 1 gload/wave/set).
// THREE independent MFMA chains per set (hh/hl/lh) for latency hiding; ei in
// LDS folded as chain-A's C-init. Score = x.e - 0.5||e||^2, argmax==argmin.
__global__ __launch_bounds__(512, 2) void vq_kernel(
        const float* __restrict__ in, const float* __restrict__ emb,
        const char* __restrict__ wsA, float* __restrict__ out) {
    __shared__ __align__(16) char stg[3][SETB];      // 24 KB ring
    __shared__ float xl[CDIM * 129];                 // 33 KB x transpose tile
    __shared__ __align__(16) float eiL[NSET * 32];   // 4 KB C-init vectors
    __shared__ int   kwin[BPOS];
    __shared__ float lred[8];

    const int tid  = threadIdx.x;
    const int lane = tid & 63, wv = tid >> 6;        // 8 waves
    const int col  = lane & 31, h = lane >> 5;       // B col / code-row half
    const int p0   = blockIdx.x * BPOS;
    const int b    = p0 >> 15;                       // 256-tile never straddles batch
    const int s0   = p0 & 32767;
    const float* xin = in + (size_t)b * (CDIM * SPATIAL) + s0;
    const float* eiG = (const float*)(wsA + EIEXP);

    // ---- prologue: eiL copy, then x->xl / B-frags in two halves of 128 pos ----
    eiL[tid] = eiG[tid];
    eiL[tid + 512] = eiG[tid + 512];

    half8 bh[4], bl[4];                              // 32 pos x 64 ch hi/lo = 32 VGPR
    for (int H = 0; H < 2; ++H) {
        {
            int p = tid & 127, cq = tid >> 7;
#pragma unroll
            for (int j = 0; j < 16; ++j) {
                int c = cq * 16 + j;
                xl[c * 129 + p] = xin[(size_t)c * SPATIAL + H * 128 + p];
            }
        }
        __syncthreads();
        if ((wv >> 2) == H) {                        // waves of this half build B-frags
            int pp = (wv & 3) * 32 + col;
#pragma unroll
            for (int ks = 0; ks < 4; ++ks)
#pragma unroll
                for (int j = 0; j < 8; ++j) {
                    int c = ks * 16 + h * 8 + j;     // B k-local = h*8+j (matches A)
                    float v = xl[c * 129 + pp];
                    _Float16 hh = (_Float16)v;
                    bh[ks][j] = hh;
                    bl[ks][j] = (_Float16)(v - (float)hh);
                }
        }
        __syncthreads();
    }

    // stage sets 0,1 LAST so they are the only outstanding vmem ops in the loop
    GLDS16(wsA + 0 * SETB + wv * 1024 + lane * 16, &stg[0][0] + wv * 1024 + lane * 16);
    GLDS16(wsA + 1 * SETB + wv * 1024 + lane * 16, &stg[1][0] + wv * 1024 + lane * 16);

    // ---- main loop: 32 sets, 3-slot ring, stage 2 ahead, vmcnt(1)/set ----
    float best = -3.402823466e38f;
    int   bk   = 0;
    char* cur = &stg[0][0];
    char* nxt = &stg[1][0];
    char* fut = &stg[2][0];
#pragma unroll 1
    for (int it = 0; it < NSET; ++it) {
        asm volatile("s_waitcnt vmcnt(1)" ::: "memory");   // set `it` staged
        __syncthreads();                                    // visible to all waves
        {   // stage set it+2 into `fut` (wrap modulo 32 at tail: harmless re-stage)
            int sN = (it + 2) & (NSET - 1);
            GLDS16(wsA + (size_t)sN * SETB + wv * 1024 + lane * 16,
                   fut + wv * 1024 + lane * 16);
        }
        // ---- consume set `it`: 3 independent chains (hh into ei-init, hl, lh) ----
        f32x16 aA = *(const f32x16*)&eiL[(it * 2 + h) * 16];
        f32x16 aB, aC;
#pragma unroll
        for (int q = 0; q < 16; ++q) { aB[q] = 0.f; aC[q] = 0.f; }
        const char* ap = cur + (size_t)lane * 16;
#pragma unroll
        for (int ks = 0; ks < 4; ++ks) {
            half8 ah = *(const half8*)(ap + (ks * 2 + 0) * 1024);
            half8 al = *(const half8*)(ap + (ks * 2 + 1) * 1024);
            aA = __builtin_amdgcn_mfma_f32_32x32x16_f16(ah, bh[ks], aA, 0, 0, 0);
            aB = __builtin_amdgcn_mfma_f32_32x32x16_f16(ah, bl[ks], aB, 0, 0, 0);
            aC = __builtin_amdgcn_mfma_f32_32x32x16_f16(al, bh[ks], aC, 0, 0, 0);
        }
        // fold: k(q) = it*32 + 4h + (q&3) + 8*(q>>2), ascending in q; sets ascend
        // -> strict > keeps smallest k within this thread's codes
        const int kbase = it * 32 + 4 * h;
#pragma unroll
        for (int q = 0; q < 16; ++q) {
            float sc = (aA[q] + aB[q]) + aC[q];
            int   kk = kbase + (q & 3) + 8 * (q >> 2);
            if (sc > best) { best = sc; bk = kk; }
        }
        char* t0 = cur; cur = nxt; nxt = fut; fut = t0;     // rotate ring
    }

    // ---- cross-h lex combine (score desc, k asc), publish winners ----
    {
        float os = __shfl_xor(best, 32);
        int   ok = __shfl_xor(bk, 32);
        if (os > best || (os == best && ok < bk)) { best = os; bk = ok; }
        if (lane < 32) {
            kwin[wv * 32 + col] = bk;
            out[OUT_IDX + p0 + wv * 32 + col] = (float)bk;
        }
    }
    __syncthreads();

    // ---- epilogue: coalesced q stores, exact f32 x re-read (L3-hot), loss ----
    float lsum = 0.f;
    {
        int p = tid & 255, cq = tid >> 8;
        int kk = kwin[p];
        const float* eb = emb + (size_t)kk * CDIM;
        float* q = out + OUT_Q + (size_t)b * (CDIM * SPATIAL) + s0;
#pragma unroll
        for (int j = 0; j < 32; ++j) {
            int c = cq * 32 + j;
            float x = xin[(size_t)c * SPATIAL + p];
            float e = eb[c];
            float d = e - x;                         // stop_grad(q - x)
            lsum = fmaf(d, d, lsum);
            q[(size_t)c * SPATIAL + p] = x + d;      // straight-through
        }
    }
#pragma unroll
    for (int off = 32; off > 0; off >>= 1) lsum += __shfl_down(lsum, off);
    if (lane == 0) lred[wv] = lsum;
    __syncthreads();
    if (tid == 0) {
        float t = 0.f;
#pragma unroll
        for (int w = 0; w < 8; ++w) t += lred[w];
        atomicAdd(out + OUT_LOSS, t * (0.25f / (float)NEL));
    }
}

extern "C" void kernel_launch(void* const* d_in, const int* in_sizes, int n_in,
                              void* d_out, int out_size, void* d_ws, size_t ws_size,
                              hipStream_t stream) {
    const float* in  = (const float*)d_in[0];   // [2,64,32,32,32] f32
    const float* emb = (const float*)d_in[1];   // [1024,64] f32
    float* out = (float*)d_out;
    char*  ws  = (char*)d_ws;                   // 266,240 B used

    prep_emb<<<64, 256, 0, stream>>>(emb, ws, out);
    vq_kernel<<<NPOS / BPOS, 512, 0, stream>>>(in, emb, ws, out);
}

// Round 10
// 42.340 us; speedup vs baseline: 2.3465x; 1.1582x over previous
//
#include <hip/hip_runtime.h>
#include <stdint.h>

#define KCODES  1024
#define CDIM    64
#define SPATIAL 32768
#define NPOS    65536
#define NEL     4194304

// d_out layout (floats), outputs concatenated in reference return order
#define OUT_Q    0
#define OUT_LOSS 4194304
#define OUT_IDX  4194305
#define OUT_SUM  4259841
#define OUT_EMB  4260097

// ws: 32 sets x 8KB {Ah0,Al0,Ah1,Al1,Ah2,Al2,Ah3,Al3} (1KB chunks, lane-linear),
// then eiExp[32][2][16] f32 at EIEXP: per-lane C-init vectors (-0.5*||e||^2)
#define NSET  32
#define SETB  8192
#define EIEXP 262144
#define BPOS  128
#define NRND  16           // rounds per wave (K-split 2: 16 sets each)

typedef _Float16 half8  __attribute__((ext_vector_type(8)));
typedef float    f32x4  __attribute__((ext_vector_type(4)));
typedef float    f32x16 __attribute__((ext_vector_type(16)));

// ---- prep: fragment-swizzle codebook (32x32x16 A-frags), eiExp, zero, passthrough ----
__global__ void prep_emb(const float* __restrict__ emb, char* __restrict__ ws,
                         float* __restrict__ out) {
    int gt = blockIdx.x * 256 + threadIdx.x;        // 64 blocks -> 0..16383
    if (gt == 0) out[OUT_LOSS] = 0.f;
    if (gt < 256) out[OUT_SUM + gt] = 0.f;
    {   // embedding passthrough (OUT_EMB odd offset -> scalar stores)
        float4 v = *(const float4*)(emb + (size_t)gt * 4);
        float* o = out + OUT_EMB + (size_t)gt * 4;
        o[0] = v.x; o[1] = v.y; o[2] = v.z; o[3] = v.w;
    }
    if (gt < 8192) {                                 // one (code, 8-ch octet) each
        int k = gt >> 3, oct = gt & 7;
        int set = k >> 5, row = k & 31;
        int ks = oct >> 1, hc = oct & 1;             // c = ks*16 + hc*8 + i
        const float* e = emb + (size_t)k * CDIM + oct * 8;
        char* rec = ws + (size_t)set * SETB;
        // A-frag: lane l = hc*32+row holds 8 fp16 at chunk(ks,hi/lo) + l*16
        _Float16* hi = (_Float16*)(rec + (ks * 2 + 0) * 1024 + (hc * 32 + row) * 16);
        _Float16* lo = (_Float16*)(rec + (ks * 2 + 1) * 1024 + (hc * 32 + row) * 16);
        float s2 = 0.f;
        half8 hv, lv;
#pragma unroll
        for (int i = 0; i < 8; ++i) {
            float v = e[i];
            s2 = fmaf(v, v, s2);
            _Float16 h = (_Float16)v;
            hv[i] = h;
            lv[i] = (_Float16)(v - (float)h);
        }
        *(half8*)hi = hv;
        *(half8*)lo = lv;
        s2 += __shfl_xor(s2, 1);                     // reduce over the octet group
        s2 += __shfl_xor(s2, 2);
        s2 += __shfl_xor(s2, 4);
        if (oct == 0) {
            // C/D row = (q&3) + 8*(q>>2) + 4h  ->  h = bit2(row), q = (row&3)|((row>>3)<<2)
            int hh = (row >> 2) & 1;
            int q  = (row & 3) | ((row >> 3) << 2);
            ((float*)(ws + EIEXP))[(set * 2 + hh) * 16 + q] = -0.5f * s2;
        }
    }
}

// async global->LDS, 16B per lane
#define GLDS16(GSRC, LDST)                                                     \
    __builtin_amdgcn_global_load_lds(                                          \
        (const __attribute__((address_space(1))) void*)(GSRC),                 \
        (__attribute__((address_space(3))) void*)(LDST), 16, 0, 0)

// ---- main VQ kernel ----
// Grid 512 x 512 thr (8 waves) = 2 blocks/CU = 4 waves/SIMD. Block owns 128
// positions. Wave (pg,kh): pg=wv&3 owns 32 positions, kh=wv>>2 scans half the
// codebook (16 sets of 32 codes) -> K-split doubles occupancy. Two staging
// streams (one per K-half), each a 3-slot LDS ring staged 2 rounds ahead via
// global_load_lds, counted vmcnt(2) per wave. Single MFMA chain per set with
// ei as first C-operand; vectorized per-q-slot argmax (no serial cmp chain).
// Score = x.e - 0.5||e||^2, argmax == argmin distance.
__global__ __launch_bounds__(512, 4) void vq_kernel(
        const float* __restrict__ in, const float* __restrict__ emb,
        const char* __restrict__ wsA, float* __restrict__ out) {
    // ring[kh][slot] : 6 x 8KB = 48KB; xl (33KB) aliases onto it (dead after prologue)
    __shared__ __align__(16) char ring[6][SETB];
    __shared__ __align__(16) float eiL[NSET * 32];   // 4KB C-init vectors
    __shared__ float candS[2][BPOS];
    __shared__ int   candK[2][BPOS];
    __shared__ int   kwin[BPOS];
    __shared__ float lred[8];

    const int tid  = threadIdx.x;
    const int lane = tid & 63, wv = tid >> 6;        // 8 waves
    const int col  = lane & 31, h = lane >> 5;
    const int pg   = wv & 3, kh = wv >> 2;           // pos-group / K-half
    const int p0   = blockIdx.x * BPOS;
    const int b    = p0 >> 15;                       // 128-tile never straddles batch
    const int s0   = p0 & 32767;
    const float* xin = in + (size_t)b * (CDIM * SPATIAL) + s0;
    const float* eiG = (const float*)(wsA + EIEXP);

    // ---- prologue: x -> xl (aliased), B-frags, eiL, then ring pre-stage ----
    float* xl = (float*)&ring[0][0];                 // 64 x 129 floats = 33KB
    {
        int p = tid & 127, cq = tid >> 7;
#pragma unroll
        for (int j = 0; j < 16; ++j) {
            int c = cq * 16 + j;
            xl[c * 129 + p] = xin[(size_t)c * SPATIAL + p];
        }
    }
    eiL[tid] = eiG[tid];
    eiL[tid + 512] = eiG[tid + 512];
    __syncthreads();

    half8 bh[4], bl[4];                              // 32 pos x 64 ch hi/lo = 32 VGPR
    {
        int pp = pg * 32 + col;
#pragma unroll
        for (int ks = 0; ks < 4; ++ks)
#pragma unroll
            for (int j = 0; j < 8; ++j) {
                int c = ks * 16 + h * 8 + j;         // B k-local = h*8+j (matches A)
                float v = xl[c * 129 + pp];
                _Float16 hh = (_Float16)v;
                bh[ks][j] = hh;
                bl[ks][j] = (_Float16)(v - (float)hh);
            }
    }
    __syncthreads();                                 // xl reads done; ring may overwrite

    // pre-stage rounds 0,1 of own stream (wave stages its pg's 2KB quarter)
    char* sl0 = &ring[kh * 3 + 0][0];
    char* sl1 = &ring[kh * 3 + 1][0];
    char* sl2 = &ring[kh * 3 + 2][0];
#define STAGE2(RSET, DST) do {                                                 \
        const char* src_ = wsA + (size_t)(RSET) * SETB + pg * 2048 + lane * 16;\
        char* dst_ = (DST) + pg * 2048 + lane * 16;                            \
        GLDS16(src_, dst_);                                                    \
        GLDS16(src_ + 1024, dst_ + 1024);                                      \
    } while (0)
    STAGE2(kh * 16 + 0, sl0);
    STAGE2(kh * 16 + 1, sl1);
    asm volatile("s_waitcnt vmcnt(2)" ::: "memory"); // round-0 data drained
    __syncthreads();

    // ---- main loop: 16 rounds, stream-private 3-slot ring, stage 2 ahead ----
    f32x16 maxS;
    int    maxR[16];
#pragma unroll
    for (int q = 0; q < 16; ++q) { maxS[q] = -3.402823466e38f; maxR[q] = 0; }

#pragma unroll 1
    for (int r = 0; r < NRND; ++r) {
        STAGE2(kh * 16 + ((r + 2) & 15), sl2);       // wraps at tail: harmless re-stage
        const int setid = kh * 16 + r;
        f32x16 eiv = *(const f32x16*)&eiL[(setid * 2 + h) * 16];
        const char* ap = sl0 + (size_t)lane * 16;
        f32x16 a;
        {
            half8 ah0 = *(const half8*)(ap);
            half8 al0 = *(const half8*)(ap + 1024);
            half8 ah1 = *(const half8*)(ap + 2048);
            half8 al1 = *(const half8*)(ap + 3072);
            half8 ah2 = *(const half8*)(ap + 4096);
            half8 al2 = *(const half8*)(ap + 5120);
            half8 ah3 = *(const half8*)(ap + 6144);
            half8 al3 = *(const half8*)(ap + 7168);
            a = __builtin_amdgcn_mfma_f32_32x32x16_f16(ah0, bh[0], eiv, 0, 0, 0);
            a = __builtin_amdgcn_mfma_f32_32x32x16_f16(ah0, bl[0], a, 0, 0, 0);
            a = __builtin_amdgcn_mfma_f32_32x32x16_f16(al0, bh[0], a, 0, 0, 0);
            a = __builtin_amdgcn_mfma_f32_32x32x16_f16(ah1, bh[1], a, 0, 0, 0);
            a = __builtin_amdgcn_mfma_f32_32x32x16_f16(ah1, bl[1], a, 0, 0, 0);
            a = __builtin_amdgcn_mfma_f32_32x32x16_f16(al1, bh[1], a, 0, 0, 0);
            a = __builtin_amdgcn_mfma_f32_32x32x16_f16(ah2, bh[2], a, 0, 0, 0);
            a = __builtin_amdgcn_mfma_f32_32x32x16_f16(ah2, bl[2], a, 0, 0, 0);
            a = __builtin_amdgcn_mfma_f32_32x32x16_f16(al2, bh[2], a, 0, 0, 0);
            a = __builtin_amdgcn_mfma_f32_32x32x16_f16(ah3, bh[3], a, 0, 0, 0);
            a = __builtin_amdgcn_mfma_f32_32x32x16_f16(ah3, bl[3], a, 0, 0, 0);
            a = __builtin_amdgcn_mfma_f32_32x32x16_f16(al3, bh[3], a, 0, 0, 0);
        }
        // vectorized per-q-slot argmax: 16 independent lanes of state, no serial chain.
        // For fixed q, k grows with r -> strict > keeps smallest k.
#pragma unroll
        for (int q = 0; q < 16; ++q)
            if (a[q] > maxS[q]) { maxS[q] = a[q]; maxR[q] = setid; }
        char* t0 = sl0; sl0 = sl1; sl1 = sl2; sl2 = t0;   // rotate ring
        asm volatile("s_waitcnt vmcnt(2)" ::: "memory");  // next round's set drained
        __syncthreads();
    }
#undef STAGE2

    // ---- per-lane lex fold over q-slots (score desc, k asc) ----
    float best = maxS[0];
    int   bk   = maxR[0] * 32 + 4 * h;
#pragma unroll
    for (int q = 1; q < 16; ++q) {
        float sc = maxS[q];
        int   kk = maxR[q] * 32 + 4 * h + (q & 3) + 8 * (q >> 2);
        if (sc > best || (sc == best && kk < bk)) { best = sc; bk = kk; }
    }
    // cross-h combine (same position, disjoint code rows)
    {
        float os = __shfl_xor(best, 32);
        int   ok = __shfl_xor(bk, 32);
        if (os > best || (os == best && ok < bk)) { best = os; bk = ok; }
    }
    if (h == 0) {
        candS[kh][pg * 32 + col] = best;
        candK[kh][pg * 32 + col] = bk;
    }
    __syncthreads();

    // ---- combine the two K-halves, write indices ----
    if (tid < BPOS) {
        float s0v = candS[0][tid], s1v = candS[1][tid];
        int   k0v = candK[0][tid], k1v = candK[1][tid];
        int sel = (s1v > s0v) || (s1v == s0v && k1v < k0v);
        int bkf = sel ? k1v : k0v;
        kwin[tid] = bkf;
        out[OUT_IDX + p0 + tid] = (float)bkf;
    }
    __syncthreads();

    // ---- epilogue: coalesced q stores, exact f32 x re-read (L2-hot), loss ----
    float lsum = 0.f;
    {
        int p = tid & 127, cq = tid >> 7;
        int kk = kwin[p];
        const float* eb = emb + (size_t)kk * CDIM;
        float* q = out + OUT_Q + (size_t)b * (CDIM * SPATIAL) + s0;
#pragma unroll
        for (int j = 0; j < 16; ++j) {
            int c = cq * 16 + j;
            float x = xin[(size_t)c * SPATIAL + p];
            float e = eb[c];
            float d = e - x;                         // stop_grad(q - x)
            lsum = fmaf(d, d, lsum);
            q[(size_t)c * SPATIAL + p] = x + d;      // straight-through
        }
    }
#pragma unroll
    for (int off = 32; off > 0; off >>= 1) lsum += __shfl_down(lsum, off);
    if (lane == 0) lred[wv] = lsum;
    __syncthreads();
    if (tid == 0) {
        float t = 0.f;
#pragma unroll
        for (int w = 0; w < 8; ++w) t += lred[w];
        atomicAdd(out + OUT_LOSS, t * (0.25f / (float)NEL));
    }
}

extern "C" void kernel_launch(void* const* d_in, const int* in_sizes, int n_in,
                              void* d_out, int out_size, void* d_ws, size_t ws_size,
                              hipStream_t stream) {
    const float* in  = (const float*)d_in[0];   // [2,64,32,32,32] f32
    const float* emb = (const float*)d_in[1];   // [1024,64] f32
    float* out = (float*)d_out;
    char*  ws  = (char*)d_ws;                   // 266,240 B used

    prep_emb<<<64, 256, 0, stream>>>(emb, ws, out);
    vq_kernel<<<NPOS / BPOS, 512, 0, stream>>>(in, emb, ws, out);
}